// Round 6
// baseline (1056.543 us; speedup 1.0000x reference)
//
#include <hip/hip_runtime.h>
#include <hip/hip_bf16.h>
#include <stdint.h>
#include <stddef.h>

#define NN 100000
#define NE 300000
#define FINDIM 128
#define HD 256
#define NG 4000
#define NLAYER 5
#define MPAD 100096   // multiple of 32; pad rows kept == 0.0f always
#define NT (MPAD/32)  // 3128 m-tiles of 32 rows
#define MG 384        // m-groups; grid = 2*MG

typedef __attribute__((ext_vector_type(8))) short bf8;
typedef __attribute__((ext_vector_type(4))) float f4;

#define FENCE() __asm__ volatile("" ::: "memory")
#define WAITVM2() __asm__ volatile("s_waitcnt vmcnt(2)" ::: "memory")
#define WAITVM4() __asm__ volatile("s_waitcnt vmcnt(4)" ::: "memory")
#define WAITVM6() __asm__ volatile("s_waitcnt vmcnt(6)" ::: "memory")
#define WAITLGKM() __asm__ volatile("s_waitcnt lgkmcnt(0)" ::: "memory")
#define BARRIER() do { FENCE(); __builtin_amdgcn_s_barrier(); FENCE(); } while(0)

__device__ __forceinline__ unsigned short f2bf(float f){
  union { float f; unsigned u; } uf; uf.f = f;
  unsigned r = uf.u + 0x7fffu + ((uf.u >> 16) & 1u);
  return (unsigned short)(r >> 16);
}
__device__ __forceinline__ float bf2f(unsigned short h){
  union { unsigned u; float f; } uf; uf.u = ((unsigned)h) << 16; return uf.f;
}

__device__ __forceinline__ void gload16(const void* g, void* l){
  __builtin_amdgcn_global_load_lds((const __attribute__((address_space(1))) void*)g,
                                   (__attribute__((address_space(3))) void*)l, 16, 0, 0);
}

// ---------------- zero fill ----------------
__global__ void k_zero(int* __restrict__ p, int n){
  int i = blockIdx.x*256 + threadIdx.x;
  if(i < n) p[i] = 0;
}

// ---------------- CSR build ----------------
__global__ void k_count(const int* __restrict__ ei, int* __restrict__ counts){
  int e = blockIdx.x*256 + threadIdx.x;
  if(e < NE) atomicAdd(&counts[ei[NE + e]], 1);
}

__global__ void k_scan_partial(const int* __restrict__ counts, int* __restrict__ partials){
  __shared__ int sw[4];
  int b = blockIdx.x, t = threadIdx.x;
  int base = b*1024 + t*4;
  int s = 0;
  #pragma unroll
  for(int j=0;j<4;j++){ int i = base+j; if(i < NN) s += counts[i]; }
  #pragma unroll
  for(int d=1; d<64; d<<=1) s += __shfl_xor(s, d, 64);
  if((t & 63) == 0) sw[t>>6] = s;
  __syncthreads();
  if(t == 0) partials[b] = sw[0]+sw[1]+sw[2]+sw[3];
}

__global__ void k_scan_tot(int* __restrict__ partials, int* __restrict__ offsets, int nb){
  __shared__ int sm[128];
  int t = threadIdx.x;
  int v = (t < nb) ? partials[t] : 0;
  sm[t] = v; __syncthreads();
  for(int d=1; d<128; d<<=1){
    int x = 0;
    if(t >= d) x = sm[t-d];
    __syncthreads();
    sm[t] += x;
    __syncthreads();
  }
  if(t < nb) partials[t] = sm[t] - v;   // exclusive
  if(t == 127) offsets[NN] = sm[127];   // total == NE
}

__global__ void k_scan_final(const int* __restrict__ counts, const int* __restrict__ partials,
                             int* __restrict__ offsets, int* __restrict__ cursor){
  __shared__ int wsum[4];
  int b = blockIdx.x, t = threadIdx.x;
  int base = b*1024 + t*4;
  int c[4]; int ts = 0;
  #pragma unroll
  for(int j=0;j<4;j++){ int i = base+j; c[j] = (i < NN) ? counts[i] : 0; ts += c[j]; }
  int lane = t & 63;
  int inc = ts;
  #pragma unroll
  for(int d=1; d<64; d<<=1){ int x = __shfl_up(inc, d, 64); if(lane >= d) inc += x; }
  if(lane == 63) wsum[t>>6] = inc;
  __syncthreads();
  int woff = 0;
  for(int w2=0; w2<(t>>6); w2++) woff += wsum[w2];
  int excl = partials[b] + woff + inc - ts;
  #pragma unroll
  for(int j=0;j<4;j++){
    int i = base+j;
    if(i < NN){ offsets[i] = excl; cursor[i] = excl; excl += c[j]; }
  }
}

__global__ void k_fill(const int* __restrict__ ei, int* __restrict__ cursor, int* __restrict__ eidx){
  int e = blockIdx.x*256 + threadIdx.x;
  if(e < NE){
    int d = ei[NE + e];
    int pos = atomicAdd(&cursor[d], 1);
    eidx[pos] = ei[e];
  }
}

// ---------------- weight transpose/convert ----------------
__global__ void k_wt(const float* __restrict__ src, unsigned short* __restrict__ dst, int K, int Ncols){
  int l = blockIdx.y;
  size_t base = (size_t)l * K * Ncols;
  int i = blockIdx.x*256 + threadIdx.x;
  if(i < K*Ncols){
    int k = i / Ncols, n = i % Ncols;
    dst[base + (size_t)n*K + k] = f2bf(src[base + i]);
  }
}

// ---------------- GEMM, B-in-regs, double-buffered gload_lds A, 4 blocks/CU ----------------
// Grid 2*MG. Block 256 thr / 4 waves; wave tile 32m x 32n. LDS 37.4 KB ->
// __launch_bounds__(256,4) gives 4 blocks/CU (R1:2blk=57us, R0/R2:3blk=43-46us;
// occupancy scaled near-linearly -> this is the lever, not sync scheduling).
// vmcnt FIFO at top of iter k: [loads(k):4][stores(k-1):2][loads(k+1):4]
//   -> steady WAITVM6; k==0: WAITVM4 (only loads(0)+loads(1)); last: WAITVM2.
// Second barrier (after all reads of buf[k&1]) makes re-DMA into it safe.
// TRANS: one-pass in-LDS BN+ReLU, scale/shift in 16 REGISTERS (thread t owns
// orig col-chunk t&31 at rows (t>>5)+8i, LDS chunk p=(t&31)^(t>>5)).
template<int TRANS, bool RELUOUT, bool STATS>
__global__ __launch_bounds__(256, 4) void k_gemmb(
    const unsigned short* __restrict__ A, const unsigned short* __restrict__ Bt,
    const float* __restrict__ bias, const float* __restrict__ preS,
    const float* __restrict__ preT, unsigned short* __restrict__ C,
    float* __restrict__ stats)
{
  __shared__ __align__(16) unsigned short As[2][8192];   // 32 KB: 2 x (32r x 256k)
  __shared__ __align__(16) unsigned short Cs[4][576];    // 4.5 KB: per-wave 16 x 36
  const int t = threadIdx.x;
  const int lane = t & 63, w = t >> 6;
  const int q = lane >> 4, ln = lane & 15;
  const int nh = blockIdx.x & 1;
  const int mg = blockIdx.x >> 1;
  const int nbase = nh*128 + w*32;

  // B fragments resident in registers (L2-resident 128 KB weight)
  bf8 bb[2][8];
  #pragma unroll
  for(int nf=0; nf<2; nf++)
    #pragma unroll
    for(int s=0; s<8; s++)
      bb[nf][s] = *(const bf8*)(Bt + (size_t)(nbase + nf*16 + ln)*HD + s*32 + q*8);

  float bv[2];
  #pragma unroll
  for(int nf=0; nf<2; nf++) bv[nf] = bias[nbase + nf*16 + ln];

  // TRANS scale/shift in registers (16 VGPR), loaded once from global
  f4 sA = (f4){0.f,0.f,0.f,0.f}, sB = sA, tA = sA, tB = sA;
  if(TRANS){
    int cc = (t & 31) * 8;
    sA = *(const f4*)(preS + cc);  sB = *(const f4*)(preS + cc + 4);
    tA = *(const f4*)(preT + cc);  tB = *(const f4*)(preT + cc + 4);
  }

  auto issueA = [&](int mt, int b){
    const int m0 = mt*32;
    #pragma unroll
    for(int j=0; j<4; j++){
      int slot = j*256 + t;
      int row = slot >> 5, p = slot & 31;
      int c = p ^ (row & 7);
      gload16(A + (size_t)(m0 + row)*HD + c*8, &As[b][(j*256 + w*64)*8]);
    }
  };

  float sacc[2] = {0.f, 0.f}, ssacc[2] = {0.f, 0.f};

  issueA(mg, 0);
  issueA(mg + MG, 1);           // mg+MG < NT always (mg<384, NT=3128)

  int k = 0;
  for(int mt = mg; mt < NT; mt += MG, k++){
    const bool last = (mt + MG >= NT);
    // retire loads(k); keep stores(k-1) + loads(k+1) in flight
    if(last)        WAITVM2();
    else if(k == 0) WAITVM4();
    else            WAITVM6();
    BARRIER();                          // tile k in LDS everywhere

    unsigned short* Ab = &As[k & 1][0];
    const int m0 = mt*32;
    const bool padt = (m0 >= NN);       // block-uniform; pad tiles are trailing

    if(padt){
      // keep output pad rows zero; 2 stores (same count as normal path)
      uint4 z = (uint4){0u,0u,0u,0u};
      int r2 = lane >> 2, sg = lane & 3;
      *(uint4*)&C[(size_t)(m0 + r2)*HD + nbase + sg*8]      = z;
      *(uint4*)&C[(size_t)(m0 + 16 + r2)*HD + nbase + sg*8] = z;
    } else {
      if(TRANS){
        // one-pass in-LDS BN+ReLU, scale/shift from regs, conflict-free sweep
        const int r0 = t >> 5;
        const int p  = (t & 31) ^ r0;
        #pragma unroll
        for(int i=0; i<4; i++){
          int row = r0 + 8*i;
          uint4 u = *(uint4*)&Ab[(row*32 + p)*8];
          unsigned short* us = (unsigned short*)&u;
          #pragma unroll
          for(int e=0; e<8; e++){
            float sc = (e<4) ? sA[e] : sB[e-4];
            float sh = (e<4) ? tA[e] : tB[e-4];
            float v = bf2f(us[e]);
            v = fmaxf(fmaf(sc, v, sh), 0.f);
            us[e] = f2bf(v);
          }
          *(uint4*)&Ab[(row*32 + p)*8] = u;
        }
        WAITLGKM();
        BARRIER();                      // transformed tile visible to all waves
      }

      f4 acc[2][2];
      #pragma unroll
      for(int i=0;i<2;i++)
        #pragma unroll
        for(int j=0;j<2;j++) acc[i][j] = (f4){0.f,0.f,0.f,0.f};

      __builtin_amdgcn_s_setprio(1);
      #pragma unroll
      for(int s=0; s<8; s++){
        bf8 af[2];
        #pragma unroll
        for(int mi=0; mi<2; mi++){
          int row = mi*16 + ln;
          int p = (s*4 + q) ^ (row & 7);
          af[mi] = *(const bf8*)&Ab[row*256 + p*8];
        }
        #pragma unroll
        for(int mi=0; mi<2; mi++)
          #pragma unroll
          for(int nf=0; nf<2; nf++)
            acc[mi][nf] = __builtin_amdgcn_mfma_f32_16x16x32_bf16(af[mi], bb[nf][s], acc[mi][nf], 0, 0, 0);
      }
      __builtin_amdgcn_s_setprio(0);

      if(STATS){
        #pragma unroll
        for(int nf=0; nf<2; nf++)
          #pragma unroll
          for(int mi=0; mi<2; mi++)
            #pragma unroll
            for(int r=0; r<4; r++){
              float v = acc[mi][nf][r];
              sacc[nf] += v; ssacc[nf] = fmaf(v, v, ssacc[nf]);
            }
      }

      // epilogue: two 16-row half-passes through a 4.5KB per-wave Cs slice
      unsigned short* wsc = &Cs[w][0];
      #pragma unroll
      for(int mi=0; mi<2; mi++){
        #pragma unroll
        for(int nf=0; nf<2; nf++)
          #pragma unroll
          for(int r=0; r<4; r++){
            float v = acc[mi][nf][r] + bv[nf];
            if(RELUOUT) v = fmaxf(v, 0.f);
            wsc[(q*4 + r)*36 + nf*16 + ln] = f2bf(v);
          }
        int r2 = lane >> 2, sg = lane & 3;
        uint4 u = *(const uint4*)&wsc[r2*36 + sg*8];
        *(uint4*)&C[(size_t)(m0 + mi*16 + r2)*HD + nbase + sg*8] = u;
      }
    }

    // all waves done reading buf[k&1] -> safe to re-DMA it with tile k+2
    WAITLGKM();
    BARRIER();
    if(mt + 2*MG < NT) issueA(mt + 2*MG, k & 1);
  }

  if(STATS){
    #pragma unroll
    for(int nf=0; nf<2; nf++){
      float s = sacc[nf], ss = ssacc[nf];
      s  += __shfl_xor(s, 16, 64);  s  += __shfl_xor(s, 32, 64);
      ss += __shfl_xor(ss, 16, 64); ss += __shfl_xor(ss, 32, 64);
      if(q == 0){
        int gn = nbase + nf*16 + ln;
        atomicAdd(&stats[gn], s);
        atomicAdd(&stats[HD + gn], ss);
      }
    }
  }
}

// ---------------- input projection (f32 A, K=128), B-in-registers ----------------
__global__ __launch_bounds__(256, 3) void k_gemmb_in(
    const float* __restrict__ A, const unsigned short* __restrict__ Bt,
    const float* __restrict__ bias, unsigned short* __restrict__ C)
{
  __shared__ __align__(16) unsigned short As[4096];      // 32 rows x 128 k = 8 KB
  __shared__ __align__(16) unsigned short Cs[4][1152];
  const int t = threadIdx.x;
  const int lane = t & 63, w = t >> 6;
  const int q = lane >> 4, ln = lane & 15;
  const int nh = blockIdx.x & 1;
  const int mg = blockIdx.x >> 1;
  const int nbase = nh*128 + w*32;

  bf8 bb[2][4];
  #pragma unroll
  for(int nf=0; nf<2; nf++)
    #pragma unroll
    for(int s=0; s<4; s++)
      bb[nf][s] = *(const bf8*)(Bt + (size_t)(nbase + nf*16 + ln)*FINDIM + s*32 + q*8);

  float bv[2];
  #pragma unroll
  for(int nf=0; nf<2; nf++) bv[nf] = bias[nbase + nf*16 + ln];

  for(int mt = mg; mt < NT; mt += MG){
    const int m0 = mt*32;
    const bool padt = (m0 >= NN);
    __syncthreads();
    #pragma unroll
    for(int j=0; j<2; j++){
      int slot = j*256 + t;
      int row = slot >> 4, p = slot & 15;
      int c = p ^ (row & 7);
      int gm = m0 + row;
      f4 v0 = (f4){0.f,0.f,0.f,0.f}, v1 = (f4){0.f,0.f,0.f,0.f};
      if(gm < NN){
        v0 = *(const f4*)&A[(size_t)gm*FINDIM + c*8];
        v1 = *(const f4*)&A[(size_t)gm*FINDIM + c*8 + 4];
      }
      ushort4 a0, a1;
      a0.x = f2bf(v0.x); a0.y = f2bf(v0.y); a0.z = f2bf(v0.z); a0.w = f2bf(v0.w);
      a1.x = f2bf(v1.x); a1.y = f2bf(v1.y); a1.z = f2bf(v1.z); a1.w = f2bf(v1.w);
      *(ushort4*)&As[row*128 + p*8]     = a0;
      *(ushort4*)&As[row*128 + p*8 + 4] = a1;
    }
    __syncthreads();

    f4 acc[2][2];
    #pragma unroll
    for(int i=0;i<2;i++)
      #pragma unroll
      for(int j=0;j<2;j++) acc[i][j] = (f4){0.f,0.f,0.f,0.f};

    #pragma unroll
    for(int s=0; s<4; s++){
      bf8 af[2];
      #pragma unroll
      for(int mi=0; mi<2; mi++){
        int row = mi*16 + ln;
        int p = (s*4 + q) ^ (row & 7);
        af[mi] = *(const bf8*)&As[row*128 + p*8];
      }
      #pragma unroll
      for(int mi=0; mi<2; mi++)
        #pragma unroll
        for(int nf=0; nf<2; nf++)
          acc[mi][nf] = __builtin_amdgcn_mfma_f32_16x16x32_bf16(af[mi], bb[nf][s], acc[mi][nf], 0, 0, 0);
    }

    unsigned short* wsc = &Cs[w][0];
    #pragma unroll
    for(int mi=0; mi<2; mi++)
      #pragma unroll
      for(int nf=0; nf<2; nf++)
        #pragma unroll
        for(int r=0; r<4; r++){
          float v = fmaxf(acc[mi][nf][r] + bv[nf], 0.f);
          if(padt) v = 0.f;
          wsc[(mi*16 + q*4 + r)*36 + nf*16 + ln] = f2bf(v);
        }
    int r2 = lane >> 1, ch = lane & 1;
    size_t cb = (size_t)(m0 + r2)*HD + nh*128 + w*32;
    uint4 u0 = *(const uint4*)&wsc[r2*36 + ch*8];
    uint4 u1 = *(const uint4*)&wsc[r2*36 + (ch+2)*8];
    *(uint4*)&C[cb + ch*8]     = u0;
    *(uint4*)&C[cb + (ch+2)*8] = u1;
  }
}

// ---------------- BN finalize (bias folded: stats are bias-free raw sums) ----------------
__global__ void k_bnfin(const float* __restrict__ cs, const float* __restrict__ bias,
                        const float* __restrict__ g, const float* __restrict__ be,
                        float* __restrict__ sc, float* __restrict__ sh){
  int c = threadIdx.x;
  float m0 = cs[c] * (1.0f/NN);
  float mean = m0 + bias[c];
  float var  = cs[HD + c] * (1.0f/NN) - m0*m0;
  float s = g[c] * rsqrtf(var + 1e-5f);
  sc[c] = s;
  sh[c] = be[c] - mean*s;
}

// ---------------- aggregation: half-wave split, 16B lanes, 4 rows in flight ----------------
__device__ __forceinline__ void acc8(f4& alo, f4& ahi, uint4 u, float wt,
                                     f4 s0, f4 s1, f4 t0, f4 t1, int ident){
  const unsigned short* us = (const unsigned short*)&u;
  float v[8];
  #pragma unroll
  for(int e=0;e<8;e++) v[e] = bf2f(us[e]);
  if(!ident){
    v[0] = fmaxf(fmaf(s0.x, v[0], t0.x), 0.f);
    v[1] = fmaxf(fmaf(s0.y, v[1], t0.y), 0.f);
    v[2] = fmaxf(fmaf(s0.z, v[2], t0.z), 0.f);
    v[3] = fmaxf(fmaf(s0.w, v[3], t0.w), 0.f);
    v[4] = fmaxf(fmaf(s1.x, v[4], t1.x), 0.f);
    v[5] = fmaxf(fmaf(s1.y, v[5], t1.y), 0.f);
    v[6] = fmaxf(fmaf(s1.z, v[6], t1.z), 0.f);
    v[7] = fmaxf(fmaf(s1.w, v[7], t1.w), 0.f);
  }
  alo.x = fmaf(wt, v[0], alo.x); alo.y = fmaf(wt, v[1], alo.y);
  alo.z = fmaf(wt, v[2], alo.z); alo.w = fmaf(wt, v[3], alo.w);
  ahi.x = fmaf(wt, v[4], ahi.x); ahi.y = fmaf(wt, v[5], ahi.y);
  ahi.z = fmaf(wt, v[6], ahi.z); ahi.w = fmaf(wt, v[7], ahi.w);
}

__global__ __launch_bounds__(256) void k_agg(const unsigned short* __restrict__ src,
    unsigned short* __restrict__ dst,
    const int* __restrict__ offs, const int* __restrict__ eidx,
    const float* __restrict__ eps, int l,
    const float* __restrict__ sc, const float* __restrict__ sh, int ident)
{
  int wv = threadIdx.x >> 6;
  int n = blockIdx.x*4 + wv;
  if(n >= NN) return;
  int lane = threadIdx.x & 63;
  int h = lane >> 5, l5 = lane & 31;
  int c = l5 * 8;

  f4 s0=(f4){0.f,0.f,0.f,0.f}, s1=s0, t0=s0, t1=s0;
  if(!ident){
    s0 = *(const f4*)(sc + c); s1 = *(const f4*)(sc + c + 4);
    t0 = *(const f4*)(sh + c); t1 = *(const f4*)(sh + c + 4);
  }
  float ep = 1.f + eps[l];

  f4 alo = (f4){0.f,0.f,0.f,0.f}, ahi = alo;
  int lo = offs[n], hi = offs[n+1];

  bool first = true;
  for(int base = lo; first || base < hi; base += 64){
    int cnt = hi - base; if(cnt > 64) cnt = 64; if(cnt < 0) cnt = 0;
    int R = cnt + (first ? 1 : 0);          // virtual rows (self included once)
    int idx = (base + lane < hi) ? eidx[base + lane] : 0;
    for(int r0 = 0; r0 < R; r0 += 4){
      int my0 = r0 + h, my1 = r0 + 2 + h;
      bool v0 = my0 < R, v1 = my1 < R;
      bool self0 = first && (my0 == 0);
      int j0 = (first ? my0 - 1 : my0) & 63;
      int j1 = (first ? my1 - 1 : my1) & 63;
      int sr0 = __shfl(idx, j0, 64);
      int sr1 = __shfl(idx, j1, 64);
      int row0 = self0 ? n : sr0;
      float w0 = self0 ? ep : 1.f;
      uint4 u0, u1;
      if(v0) u0 = *(const uint4*)(src + (size_t)row0*HD + c);
      if(v1) u1 = *(const uint4*)(src + (size_t)sr1*HD + c);
      if(v0) acc8(alo, ahi, u0, w0, s0, s1, t0, t1, ident);
      if(v1) acc8(alo, ahi, u1, 1.f, s0, s1, t0, t1, ident);
    }
    first = false;
  }

  // merge the two halves (lane l and l^32 hold the same channel set)
  #pragma unroll
  for(int e=0;e<4;e++){
    alo[e] += __shfl_xor(alo[e], 32, 64);
    ahi[e] += __shfl_xor(ahi[e], 32, 64);
  }
  if(h == 0){
    unsigned short o[8];
    o[0]=f2bf(alo.x); o[1]=f2bf(alo.y); o[2]=f2bf(alo.z); o[3]=f2bf(alo.w);
    o[4]=f2bf(ahi.x); o[5]=f2bf(ahi.y); o[6]=f2bf(ahi.z); o[7]=f2bf(ahi.w);
    *(uint4*)(dst + (size_t)n*HD + c) = *(const uint4*)o;
  }
}

// ---------------- pooling ----------------
__device__ __forceinline__ int lowb(const int* __restrict__ arr, int n, int key){
  int lo = 0, hi = n;
  while(lo < hi){ int mid = (lo + hi) >> 1; if(arr[mid] < key) lo = mid + 1; else hi = mid; }
  return lo;
}

__global__ __launch_bounds__(256) void k_pool(const unsigned short* __restrict__ src,
    const int* __restrict__ batch,
    const float* __restrict__ sc, const float* __restrict__ sh, float* __restrict__ pooled)
{
  int wv = threadIdx.x >> 6;
  int g = blockIdx.x*4 + wv;
  if(g >= NG) return;
  int lane = threadIdx.x & 63;
  int c = lane << 2;
  int lo = lowb(batch, NN, g);
  int hi = lowb(batch, NN, g+1);
  f4 s4 = *(const f4*)(sc + c);
  f4 t4 = *(const f4*)(sh + c);
  f4 acc = (f4){0.f,0.f,0.f,0.f};
  for(int n=lo; n<hi; n++){
    ushort4 uv = *(const ushort4*)(src + (size_t)n*HD + c);
    acc.x += fmaxf(fmaf(s4.x, bf2f(uv.x), t4.x), 0.f);
    acc.y += fmaxf(fmaf(s4.y, bf2f(uv.y), t4.y), 0.f);
    acc.z += fmaxf(fmaf(s4.z, bf2f(uv.z), t4.z), 0.f);
    acc.w += fmaxf(fmaf(s4.w, bf2f(uv.w), t4.w), 0.f);
  }
  float inv = 1.0f / fmaxf((float)(hi - lo), 1.0f);
  acc.x *= inv; acc.y *= inv; acc.z *= inv; acc.w *= inv;
  *(f4*)(pooled + (size_t)g*HD + c) = acc;
}

// ---------------- head ----------------
__global__ __launch_bounds__(128) void k_head(const float* __restrict__ pooled,
    const float* __restrict__ W1, const float* __restrict__ b1,
    const float* __restrict__ W2, const float* __restrict__ b2, float* __restrict__ out)
{
  __shared__ float p[HD];
  __shared__ float red[2];
  int g = blockIdx.x, t = threadIdx.x;
  if(t < 64) *(f4*)&p[t*4] = *(const f4*)(pooled + (size_t)g*HD + t*4);
  __syncthreads();
  float s = b1[t];
  for(int k=0;k<HD;k++) s = fmaf(p[k], W1[k*128 + t], s);
  float o = fmaxf(s, 0.f) * W2[t];
  #pragma unroll
  for(int d=1; d<64; d<<=1) o += __shfl_xor(o, d, 64);
  if((t & 63) == 0) red[t>>6] = o;
  __syncthreads();
  if(t == 0) out[g] = red[0] + red[1] + b2[0];
}

// ---------------- launch ----------------
extern "C" void kernel_launch(void* const* d_in, const int* in_sizes, int n_in,
                              void* d_out, int out_size, void* d_ws, size_t ws_size,
                              hipStream_t stream) {
  const float* x    = (const float*)d_in[0];
  const int*   ei   = (const int*)  d_in[1];
  const int*   bat  = (const int*)  d_in[2];
  const float* inW  = (const float*)d_in[3];
  const float* inb  = (const float*)d_in[4];
  const float* W1   = (const float*)d_in[5];
  const float* b1   = (const float*)d_in[6];
  const float* g1   = (const float*)d_in[7];
  const float* be1  = (const float*)d_in[8];
  const float* W2   = (const float*)d_in[9];
  const float* b2   = (const float*)d_in[10];
  const float* g2   = (const float*)d_in[11];
  const float* be2  = (const float*)d_in[12];
  const float* eps  = (const float*)d_in[13];
  const float* hW1  = (const float*)d_in[14];
  const float* hb1  = (const float*)d_in[15];
  const float* hW2  = (const float*)d_in[16];
  const float* hb2  = (const float*)d_in[17];
  float* out = (float*)d_out;

  char* p = (char*)d_ws;
  auto alloc = [&](size_t bytes)->char*{
    char* r = p; p += (bytes + 255) & ~(size_t)255; return r;
  };
  unsigned short* B0 = (unsigned short*)alloc((size_t)MPAD*HD*2);
  unsigned short* B1 = (unsigned short*)alloc((size_t)MPAD*HD*2);
  unsigned short* Wtin = (unsigned short*)alloc((size_t)FINDIM*HD*2);
  unsigned short* Wt1  = (unsigned short*)alloc((size_t)NLAYER*HD*HD*2);
  unsigned short* Wt2  = (unsigned short*)alloc((size_t)NLAYER*HD*HD*2);
  int* counts  = (int*)alloc((size_t)NN*4);
  int* offsets = (int*)alloc((size_t)(NN+1)*4);
  int* cursor  = (int*)alloc((size_t)NN*4);
  int* eidx    = (int*)alloc((size_t)NE*4);
  int* partials= (int*)alloc(128*4);
  float* cs    = (float*)alloc(4*HD*4);
  float* bnp   = (float*)alloc(4*HD*4);
  float* pooled= (float*)alloc((size_t)NG*HD*4);

  // CSR build
  k_zero<<<(NN+255)/256, 256, 0, stream>>>(counts, NN);
  k_count<<<(NE+255)/256, 256, 0, stream>>>(ei, counts);
  int nb = (NN + 1023)/1024;
  k_scan_partial<<<nb, 256, 0, stream>>>(counts, partials);
  k_scan_tot<<<1, 128, 0, stream>>>(partials, offsets, nb);
  k_scan_final<<<nb, 256, 0, stream>>>(counts, partials, offsets, cursor);
  k_fill<<<(NE+255)/256, 256, 0, stream>>>(ei, cursor, eidx);

  // weights -> bf16 [n][k]
  k_wt<<<dim3((FINDIM*HD+255)/256, 1), 256, 0, stream>>>(inW, Wtin, FINDIM, HD);
  k_wt<<<dim3((HD*HD+255)/256, NLAYER), 256, 0, stream>>>(W1, Wt1, HD, HD);
  k_wt<<<dim3((HD*HD+255)/256, NLAYER), 256, 0, stream>>>(W2, Wt2, HD, HD);

  // zero pad rows of B1 once (B0's pad established by gemm_in epilogue)
  {
    int padInts = (MPAD - NN) * HD / 2;
    k_zero<<<(padInts+255)/256, 256, 0, stream>>>((int*)(B1 + (size_t)NN*HD), padInts);
  }

  k_gemmb_in<<<2*MG, 256, 0, stream>>>(x, Wtin, inb, B0);

  float* sc1 = bnp, *sh1 = bnp + HD, *sc2 = bnp + 2*HD, *sh2 = bnp + 3*HD;
  unsigned short* hbuf = B0;
  unsigned short* tbuf = B1;
  for(int l=0; l<NLAYER; l++){
    k_zero<<<4, 256, 0, stream>>>((int*)cs, 4*HD);
    k_agg<<<(NN+3)/4, 256, 0, stream>>>(hbuf, tbuf, offsets, eidx, eps, l, sc2, sh2, l==0 ? 1 : 0);
    k_gemmb<0, false, true><<<2*MG, 256, 0, stream>>>(tbuf, Wt1 + (size_t)l*HD*HD, b1 + l*HD,
                                                      nullptr, nullptr, hbuf, cs);
    k_bnfin<<<1, HD, 0, stream>>>(cs, b1 + l*HD, g1 + l*HD, be1 + l*HD, sc1, sh1);
    k_gemmb<1, false, true><<<2*MG, 256, 0, stream>>>(hbuf, Wt2 + (size_t)l*HD*HD, b2 + l*HD,
                                                      sc1, sh1, tbuf, cs + 2*HD);
    k_bnfin<<<1, HD, 0, stream>>>(cs + 2*HD, b2 + l*HD, g2 + l*HD, be2 + l*HD, sc2, sh2);
    unsigned short* tmp = hbuf; hbuf = tbuf; tbuf = tmp;
  }

  k_pool<<<(NG+3)/4, 256, 0, stream>>>(hbuf, bat, sc2, sh2, pooled);
  k_head<<<NG, 128, 0, stream>>>(pooled, hW1, hb1, hW2, hb2, out);
}

// Round 7
// 818.779 us; speedup vs baseline: 1.2904x; 1.2904x over previous
//
#include <hip/hip_runtime.h>
#include <hip/hip_bf16.h>
#include <stdint.h>
#include <stddef.h>

#define NN 100000
#define NE 300000
#define FINDIM 128
#define HD 256
#define NG 4000
#define NLAYER 5
#define MPAD 100096   // multiple of 32; NN%32==0 so tiles are fully real or fully pad
#define NT (MPAD/32)  // 3128 m-tiles of 32 rows
#define MG 384        // m-groups; grid = 2*MG

typedef __attribute__((ext_vector_type(8))) short bf8;
typedef __attribute__((ext_vector_type(4))) float f4;

#define FENCE() __asm__ volatile("" ::: "memory")
#define WAITVM2() __asm__ volatile("s_waitcnt vmcnt(2)" ::: "memory")
#define WAITVM4() __asm__ volatile("s_waitcnt vmcnt(4)" ::: "memory")
#define WAITVM6() __asm__ volatile("s_waitcnt vmcnt(6)" ::: "memory")
#define WAITLGKM() __asm__ volatile("s_waitcnt lgkmcnt(0)" ::: "memory")
#define BARRIER() do { FENCE(); __builtin_amdgcn_s_barrier(); FENCE(); } while(0)

__device__ __forceinline__ unsigned short f2bf(float f){
  union { float f; unsigned u; } uf; uf.f = f;
  unsigned r = uf.u + 0x7fffu + ((uf.u >> 16) & 1u);
  return (unsigned short)(r >> 16);
}
__device__ __forceinline__ float bf2f(unsigned short h){
  union { unsigned u; float f; } uf; uf.u = ((unsigned)h) << 16; return uf.f;
}

__device__ __forceinline__ void gload16(const void* g, void* l){
  __builtin_amdgcn_global_load_lds((const __attribute__((address_space(1))) void*)g,
                                   (__attribute__((address_space(3))) void*)l, 16, 0, 0);
}

// inline BN finalize: raw bias-free sums -> scale/shift for one channel
__device__ __forceinline__ void bncoef(const float* __restrict__ st,
                                       const float* __restrict__ bb,
                                       const float* __restrict__ gg,
                                       const float* __restrict__ be,
                                       int ch, float& s, float& sh){
  float m0 = st[ch] * (1.0f/NN);
  float mean = m0 + bb[ch];
  float var  = st[HD + ch] * (1.0f/NN) - m0*m0;
  s  = gg[ch] * rsqrtf(var + 1e-5f);
  sh = be[ch] - mean*s;
}

// ---------------- zero fill ----------------
__global__ void k_zero(int* __restrict__ p, int n){
  int i = blockIdx.x*256 + threadIdx.x;
  if(i < n) p[i] = 0;
}

// ---------------- CSR build ----------------
__global__ void k_count(const int* __restrict__ ei, int* __restrict__ counts){
  int e = blockIdx.x*256 + threadIdx.x;
  if(e < NE) atomicAdd(&counts[ei[NE + e]], 1);
}

__global__ void k_scan_partial(const int* __restrict__ counts, int* __restrict__ partials){
  __shared__ int sw[4];
  int b = blockIdx.x, t = threadIdx.x;
  int base = b*1024 + t*4;
  int s = 0;
  #pragma unroll
  for(int j=0;j<4;j++){ int i = base+j; if(i < NN) s += counts[i]; }
  #pragma unroll
  for(int d=1; d<64; d<<=1) s += __shfl_xor(s, d, 64);
  if((t & 63) == 0) sw[t>>6] = s;
  __syncthreads();
  if(t == 0) partials[b] = sw[0]+sw[1]+sw[2]+sw[3];
}

__global__ void k_scan_tot(int* __restrict__ partials, int* __restrict__ offsets, int nb){
  __shared__ int sm[128];
  int t = threadIdx.x;
  int v = (t < nb) ? partials[t] : 0;
  sm[t] = v; __syncthreads();
  for(int d=1; d<128; d<<=1){
    int x = 0;
    if(t >= d) x = sm[t-d];
    __syncthreads();
    sm[t] += x;
    __syncthreads();
  }
  if(t < nb) partials[t] = sm[t] - v;   // exclusive
  if(t == 127) offsets[NN] = sm[127];   // total == NE
}

__global__ void k_scan_final(const int* __restrict__ counts, const int* __restrict__ partials,
                             int* __restrict__ offsets, int* __restrict__ cursor){
  __shared__ int wsum[4];
  int b = blockIdx.x, t = threadIdx.x;
  int base = b*1024 + t*4;
  int c[4]; int ts = 0;
  #pragma unroll
  for(int j=0;j<4;j++){ int i = base+j; c[j] = (i < NN) ? counts[i] : 0; ts += c[j]; }
  int lane = t & 63;
  int inc = ts;
  #pragma unroll
  for(int d=1; d<64; d<<=1){ int x = __shfl_up(inc, d, 64); if(lane >= d) inc += x; }
  if(lane == 63) wsum[t>>6] = inc;
  __syncthreads();
  int woff = 0;
  for(int w2=0; w2<(t>>6); w2++) woff += wsum[w2];
  int excl = partials[b] + woff + inc - ts;
  #pragma unroll
  for(int j=0;j<4;j++){
    int i = base+j;
    if(i < NN){ offsets[i] = excl; cursor[i] = excl; excl += c[j]; }
  }
}

__global__ void k_fill(const int* __restrict__ ei, int* __restrict__ cursor, int* __restrict__ eidx){
  int e = blockIdx.x*256 + threadIdx.x;
  if(e < NE){
    int d = ei[NE + e];
    int pos = atomicAdd(&cursor[d], 1);
    eidx[pos] = ei[e];
  }
}

// ---------------- weight transpose/convert ----------------
__global__ void k_wt(const float* __restrict__ src, unsigned short* __restrict__ dst, int K, int Ncols){
  int l = blockIdx.y;
  size_t base = (size_t)l * K * Ncols;
  int i = blockIdx.x*256 + threadIdx.x;
  if(i < K*Ncols){
    int k = i / Ncols, n = i % Ncols;
    dst[base + (size_t)n*K + k] = f2bf(src[base + i]);
  }
}

// ---------------- GEMM, B-in-regs, triple-buffered A, ONE barrier per tile ----------------
// R2-verified schedule (43.3us): 3 rotating 16KB A-buffers, counted vmcnt
// (steady 6 / first 4 / last 2), single top barrier per tile, DMA(k+2) into
// buf[(k-1)%3] after the body. launch_bounds(256,3): VGPR ~84, no spill
// (R6 lesson: (256,4) made the compiler pick 64 VGPR and spill bb[] ->
// +70MB FETCH / +24MB WRITE / 74us. Do not raise occupancy via bounds.)
// TRANS: BN coef computed INLINE from raw stats (k_bnfin deleted); thread t
// owns orig col-chunk t&31 (rows (t>>5)+8i at LDS chunk p=(t&31)^(t>>5)).
// zstats: block 0 zeroes the NEXT stats buffer (deletes k_zero launches).
template<int TRANS, bool RELUOUT, bool STATS>
__global__ __launch_bounds__(256, 3) void k_gemmb(
    const unsigned short* __restrict__ A, const unsigned short* __restrict__ Bt,
    const float* __restrict__ bias, const float* __restrict__ bstats,
    const float* __restrict__ bnb, const float* __restrict__ bng,
    const float* __restrict__ bnbe, unsigned short* __restrict__ C,
    float* __restrict__ stats, float* __restrict__ zstats)
{
  __shared__ __align__(16) unsigned short As[3][8192];   // 48 KB: 3 x (32r x 256k)
  __shared__ __align__(16) unsigned short Cs[4][576];    // 4.5 KB: per-wave 16 x 36
  const int t = threadIdx.x;
  const int lane = t & 63, w = t >> 6;
  const int q = lane >> 4, ln = lane & 15;
  const int nh = blockIdx.x & 1;
  const int mg = blockIdx.x >> 1;
  const int nbase = nh*128 + w*32;

  if(zstats && blockIdx.x == 0){ zstats[t] = 0.f; zstats[256 + t] = 0.f; }

  // B fragments resident in registers (L2-resident 128 KB weight)
  bf8 bb[2][8];
  #pragma unroll
  for(int nf=0; nf<2; nf++)
    #pragma unroll
    for(int s=0; s<8; s++)
      bb[nf][s] = *(const bf8*)(Bt + (size_t)(nbase + nf*16 + ln)*HD + s*32 + q*8);

  float bv[2];
  #pragma unroll
  for(int nf=0; nf<2; nf++) bv[nf] = bias[nbase + nf*16 + ln];

  // TRANS scale/shift computed inline from raw stats (16 VGPR resident)
  f4 sA = (f4){0.f,0.f,0.f,0.f}, sB = sA, tA = sA, tB = sA;
  if(TRANS){
    int cc = (t & 31) * 8;
    #pragma unroll
    for(int e=0; e<8; e++){
      float sv, sh;
      bncoef(bstats, bnb, bng, bnbe, cc + e, sv, sh);
      if(e < 4){ sA[e] = sv; tA[e] = sh; }
      else     { sB[e-4] = sv; tB[e-4] = sh; }
    }
  }

  auto issueA = [&](int mt, int b){
    const int m0 = mt*32;
    #pragma unroll
    for(int j=0; j<4; j++){
      int slot = j*256 + t;
      int row = slot >> 5, p = slot & 31;
      int c = p ^ (row & 7);
      gload16(A + (size_t)(m0 + row)*HD + c*8, &As[b][(j*256 + w*64)*8]);
    }
  };

  float sacc[2] = {0.f, 0.f}, ssacc[2] = {0.f, 0.f};

  issueA(mg, 0);
  issueA(mg + MG, 1);           // mg+MG < NT always (mg<384, NT=3128)

  int k = 0;
  for(int mt = mg; mt < NT; mt += MG, k++){
    const bool last = (mt + MG >= NT);
    // retire DMA(k); keep DMA(k+1) + prior stores in flight
    if(last)        WAITVM2();
    else if(k == 0) WAITVM4();
    else            WAITVM6();
    BARRIER();                          // tile k in LDS everywhere; tile k-1 fully read

    unsigned short* Ab = &As[k % 3][0];
    const int m0 = mt*32;
    const bool padt = (m0 >= NN);       // block-uniform; pad tiles are trailing

    if(padt){
      // keep output pad rows zero; skip compute/stats
      uint4 z = (uint4){0u,0u,0u,0u};
      int r2 = lane >> 2, sg = lane & 3;
      *(uint4*)&C[(size_t)(m0 + r2)*HD + nbase + sg*8]      = z;
      *(uint4*)&C[(size_t)(m0 + 16 + r2)*HD + nbase + sg*8] = z;
    } else {
      if(TRANS){
        // one-pass in-LDS BN+ReLU, scale/shift from regs, conflict-free sweep
        const int r0 = t >> 5;
        const int p  = (t & 31) ^ r0;
        #pragma unroll
        for(int i=0; i<4; i++){
          int row = r0 + 8*i;
          uint4 u = *(uint4*)&Ab[(row*32 + p)*8];
          unsigned short* us = (unsigned short*)&u;
          #pragma unroll
          for(int e=0; e<8; e++){
            float sc = (e<4) ? sA[e] : sB[e-4];
            float sh = (e<4) ? tA[e] : tB[e-4];
            float v = bf2f(us[e]);
            v = fmaxf(fmaf(sc, v, sh), 0.f);
            us[e] = f2bf(v);
          }
          *(uint4*)&Ab[(row*32 + p)*8] = u;
        }
        WAITLGKM();
        BARRIER();                      // transformed tile visible to all waves
      }

      f4 acc[2][2];
      #pragma unroll
      for(int i=0;i<2;i++)
        #pragma unroll
        for(int j=0;j<2;j++) acc[i][j] = (f4){0.f,0.f,0.f,0.f};

      __builtin_amdgcn_s_setprio(1);
      #pragma unroll
      for(int s=0; s<8; s++){
        bf8 af[2];
        #pragma unroll
        for(int mi=0; mi<2; mi++){
          int row = mi*16 + ln;
          int p = (s*4 + q) ^ (row & 7);
          af[mi] = *(const bf8*)&Ab[row*256 + p*8];
        }
        #pragma unroll
        for(int mi=0; mi<2; mi++)
          #pragma unroll
          for(int nf=0; nf<2; nf++)
            acc[mi][nf] = __builtin_amdgcn_mfma_f32_16x16x32_bf16(af[mi], bb[nf][s], acc[mi][nf], 0, 0, 0);
      }
      __builtin_amdgcn_s_setprio(0);

      if(STATS){
        #pragma unroll
        for(int nf=0; nf<2; nf++)
          #pragma unroll
          for(int mi=0; mi<2; mi++)
            #pragma unroll
            for(int r=0; r<4; r++){
              float v = acc[mi][nf][r];
              sacc[nf] += v; ssacc[nf] = fmaf(v, v, ssacc[nf]);
            }
      }

      // epilogue: two 16-row half-passes through a 4.5KB per-wave Cs slice
      unsigned short* wsc = &Cs[w][0];
      #pragma unroll
      for(int mi=0; mi<2; mi++){
        #pragma unroll
        for(int nf=0; nf<2; nf++)
          #pragma unroll
          for(int r=0; r<4; r++){
            float v = acc[mi][nf][r] + bv[nf];
            if(RELUOUT) v = fmaxf(v, 0.f);
            wsc[(q*4 + r)*36 + nf*16 + ln] = f2bf(v);
          }
        int r2 = lane >> 2, sg = lane & 3;
        uint4 u = *(const uint4*)&wsc[r2*36 + sg*8];
        *(uint4*)&C[(size_t)(m0 + mi*16 + r2)*HD + nbase + sg*8] = u;
      }
    }

    // DMA(k+2) into buf[(k+2)%3] == buf[(k-1)%3]: safe, all waves passed the
    // top barrier of k, so tile k-1 is fully consumed. No second barrier.
    FENCE();
    if(mt + 2*MG < NT) issueA(mt + 2*MG, (k+2) % 3);
  }

  if(STATS){
    #pragma unroll
    for(int nf=0; nf<2; nf++){
      float s = sacc[nf], ss = ssacc[nf];
      s  += __shfl_xor(s, 16, 64);  s  += __shfl_xor(s, 32, 64);
      ss += __shfl_xor(ss, 16, 64); ss += __shfl_xor(ss, 32, 64);
      if(q == 0){
        int gn = nbase + nf*16 + ln;
        atomicAdd(&stats[gn], s);
        atomicAdd(&stats[HD + gn], ss);
      }
    }
  }
}

// ---------------- input projection (f32 A, K=128), B-in-registers ----------------
__global__ __launch_bounds__(256, 3) void k_gemmb_in(
    const float* __restrict__ A, const unsigned short* __restrict__ Bt,
    const float* __restrict__ bias, unsigned short* __restrict__ C)
{
  __shared__ __align__(16) unsigned short As[4096];      // 32 rows x 128 k = 8 KB
  __shared__ __align__(16) unsigned short Cs[4][1152];
  const int t = threadIdx.x;
  const int lane = t & 63, w = t >> 6;
  const int q = lane >> 4, ln = lane & 15;
  const int nh = blockIdx.x & 1;
  const int mg = blockIdx.x >> 1;
  const int nbase = nh*128 + w*32;

  bf8 bb[2][4];
  #pragma unroll
  for(int nf=0; nf<2; nf++)
    #pragma unroll
    for(int s=0; s<4; s++)
      bb[nf][s] = *(const bf8*)(Bt + (size_t)(nbase + nf*16 + ln)*FINDIM + s*32 + q*8);

  float bv[2];
  #pragma unroll
  for(int nf=0; nf<2; nf++) bv[nf] = bias[nbase + nf*16 + ln];

  for(int mt = mg; mt < NT; mt += MG){
    const int m0 = mt*32;
    const bool padt = (m0 >= NN);
    __syncthreads();
    #pragma unroll
    for(int j=0; j<2; j++){
      int slot = j*256 + t;
      int row = slot >> 4, p = slot & 15;
      int c = p ^ (row & 7);
      int gm = m0 + row;
      f4 v0 = (f4){0.f,0.f,0.f,0.f}, v1 = (f4){0.f,0.f,0.f,0.f};
      if(gm < NN){
        v0 = *(const f4*)&A[(size_t)gm*FINDIM + c*8];
        v1 = *(const f4*)&A[(size_t)gm*FINDIM + c*8 + 4];
      }
      ushort4 a0, a1;
      a0.x = f2bf(v0.x); a0.y = f2bf(v0.y); a0.z = f2bf(v0.z); a0.w = f2bf(v0.w);
      a1.x = f2bf(v1.x); a1.y = f2bf(v1.y); a1.z = f2bf(v1.z); a1.w = f2bf(v1.w);
      *(ushort4*)&As[row*128 + p*8]     = a0;
      *(ushort4*)&As[row*128 + p*8 + 4] = a1;
    }
    __syncthreads();

    f4 acc[2][2];
    #pragma unroll
    for(int i=0;i<2;i++)
      #pragma unroll
      for(int j=0;j<2;j++) acc[i][j] = (f4){0.f,0.f,0.f,0.f};

    #pragma unroll
    for(int s=0; s<4; s++){
      bf8 af[2];
      #pragma unroll
      for(int mi=0; mi<2; mi++){
        int row = mi*16 + ln;
        int p = (s*4 + q) ^ (row & 7);
        af[mi] = *(const bf8*)&As[row*128 + p*8];
      }
      #pragma unroll
      for(int mi=0; mi<2; mi++)
        #pragma unroll
        for(int nf=0; nf<2; nf++)
          acc[mi][nf] = __builtin_amdgcn_mfma_f32_16x16x32_bf16(af[mi], bb[nf][s], acc[mi][nf], 0, 0, 0);
    }

    unsigned short* wsc = &Cs[w][0];
    #pragma unroll
    for(int mi=0; mi<2; mi++)
      #pragma unroll
      for(int nf=0; nf<2; nf++)
        #pragma unroll
        for(int r=0; r<4; r++){
          float v = fmaxf(acc[mi][nf][r] + bv[nf], 0.f);
          if(padt) v = 0.f;
          wsc[(mi*16 + q*4 + r)*36 + nf*16 + ln] = f2bf(v);
        }
    int r2 = lane >> 1, ch = lane & 1;
    size_t cb = (size_t)(m0 + r2)*HD + nh*128 + w*32;
    uint4 u0 = *(const uint4*)&wsc[r2*36 + ch*8];
    uint4 u1 = *(const uint4*)&wsc[r2*36 + (ch+2)*8];
    *(uint4*)&C[cb + ch*8]     = u0;
    *(uint4*)&C[cb + (ch+2)*8] = u1;
  }
}

// ---------------- aggregation: half-wave split, 16B lanes, inline BN coef ----------------
__device__ __forceinline__ void acc8(f4& alo, f4& ahi, uint4 u, float wt,
                                     f4 s0, f4 s1, f4 t0, f4 t1, int ident){
  const unsigned short* us = (const unsigned short*)&u;
  float v[8];
  #pragma unroll
  for(int e=0;e<8;e++) v[e] = bf2f(us[e]);
  if(!ident){
    v[0] = fmaxf(fmaf(s0.x, v[0], t0.x), 0.f);
    v[1] = fmaxf(fmaf(s0.y, v[1], t0.y), 0.f);
    v[2] = fmaxf(fmaf(s0.z, v[2], t0.z), 0.f);
    v[3] = fmaxf(fmaf(s0.w, v[3], t0.w), 0.f);
    v[4] = fmaxf(fmaf(s1.x, v[4], t1.x), 0.f);
    v[5] = fmaxf(fmaf(s1.y, v[5], t1.y), 0.f);
    v[6] = fmaxf(fmaf(s1.z, v[6], t1.z), 0.f);
    v[7] = fmaxf(fmaf(s1.w, v[7], t1.w), 0.f);
  }
  alo.x = fmaf(wt, v[0], alo.x); alo.y = fmaf(wt, v[1], alo.y);
  alo.z = fmaf(wt, v[2], alo.z); alo.w = fmaf(wt, v[3], alo.w);
  ahi.x = fmaf(wt, v[4], ahi.x); ahi.y = fmaf(wt, v[5], ahi.y);
  ahi.z = fmaf(wt, v[6], ahi.z); ahi.w = fmaf(wt, v[7], ahi.w);
}

__global__ __launch_bounds__(256) void k_agg(const unsigned short* __restrict__ src,
    unsigned short* __restrict__ dst,
    const int* __restrict__ offs, const int* __restrict__ eidx,
    const float* __restrict__ eps, int l,
    const float* __restrict__ bstats, const float* __restrict__ bnb,
    const float* __restrict__ bng, const float* __restrict__ bnbe,
    float* __restrict__ zstats, int ident)
{
  if(blockIdx.x == 0){ zstats[threadIdx.x] = 0.f; zstats[256 + threadIdx.x] = 0.f; }

  int wv = threadIdx.x >> 6;
  int n = blockIdx.x*4 + wv;
  if(n >= NN) return;
  int lane = threadIdx.x & 63;
  int h = lane >> 5, l5 = lane & 31;
  int c = l5 * 8;

  f4 s0=(f4){0.f,0.f,0.f,0.f}, s1=s0, t0=s0, t1=s0;
  if(!ident){
    #pragma unroll
    for(int e=0; e<8; e++){
      float sv, sh;
      bncoef(bstats, bnb, bng, bnbe, c + e, sv, sh);
      if(e < 4){ s0[e] = sv; t0[e] = sh; }
      else     { s1[e-4] = sv; t1[e-4] = sh; }
    }
  }
  float ep = 1.f + eps[l];

  f4 alo = (f4){0.f,0.f,0.f,0.f}, ahi = alo;
  int lo = offs[n], hi = offs[n+1];

  bool first = true;
  for(int base = lo; first || base < hi; base += 64){
    int cnt = hi - base; if(cnt > 64) cnt = 64; if(cnt < 0) cnt = 0;
    int R = cnt + (first ? 1 : 0);          // virtual rows (self included once)
    int idx = (base + lane < hi) ? eidx[base + lane] : 0;
    for(int r0 = 0; r0 < R; r0 += 4){
      int my0 = r0 + h, my1 = r0 + 2 + h;
      bool v0 = my0 < R, v1 = my1 < R;
      bool self0 = first && (my0 == 0);
      int j0 = (first ? my0 - 1 : my0) & 63;
      int j1 = (first ? my1 - 1 : my1) & 63;
      int sr0 = __shfl(idx, j0, 64);
      int sr1 = __shfl(idx, j1, 64);
      int row0 = self0 ? n : sr0;
      float w0 = self0 ? ep : 1.f;
      uint4 u0, u1;
      if(v0) u0 = *(const uint4*)(src + (size_t)row0*HD + c);
      if(v1) u1 = *(const uint4*)(src + (size_t)sr1*HD + c);
      if(v0) acc8(alo, ahi, u0, w0, s0, s1, t0, t1, ident);
      if(v1) acc8(alo, ahi, u1, 1.f, s0, s1, t0, t1, ident);
    }
    first = false;
  }

  // merge the two halves (lane l and l^32 hold the same channel set)
  #pragma unroll
  for(int e=0;e<4;e++){
    alo[e] += __shfl_xor(alo[e], 32, 64);
    ahi[e] += __shfl_xor(ahi[e], 32, 64);
  }
  if(h == 0){
    unsigned short o[8];
    o[0]=f2bf(alo.x); o[1]=f2bf(alo.y); o[2]=f2bf(alo.z); o[3]=f2bf(alo.w);
    o[4]=f2bf(ahi.x); o[5]=f2bf(ahi.y); o[6]=f2bf(ahi.z); o[7]=f2bf(ahi.w);
    *(uint4*)(dst + (size_t)n*HD + c) = *(const uint4*)o;
  }
}

// ---------------- pooling (inline BN coef) ----------------
__device__ __forceinline__ int lowb(const int* __restrict__ arr, int n, int key){
  int lo = 0, hi = n;
  while(lo < hi){ int mid = (lo + hi) >> 1; if(arr[mid] < key) lo = mid + 1; else hi = mid; }
  return lo;
}

__global__ __launch_bounds__(256) void k_pool(const unsigned short* __restrict__ src,
    const int* __restrict__ batch,
    const float* __restrict__ bstats, const float* __restrict__ bnb,
    const float* __restrict__ bng, const float* __restrict__ bnbe,
    float* __restrict__ pooled)
{
  int wv = threadIdx.x >> 6;
  int g = blockIdx.x*4 + wv;
  if(g >= NG) return;
  int lane = threadIdx.x & 63;
  int c = lane << 2;
  int lo = lowb(batch, NN, g);
  int hi = lowb(batch, NN, g+1);
  f4 s4, t4;
  #pragma unroll
  for(int e=0; e<4; e++){
    float sv, sh;
    bncoef(bstats, bnb, bng, bnbe, c + e, sv, sh);
    s4[e] = sv; t4[e] = sh;
  }
  f4 acc = (f4){0.f,0.f,0.f,0.f};
  for(int n=lo; n<hi; n++){
    ushort4 uv = *(const ushort4*)(src + (size_t)n*HD + c);
    acc.x += fmaxf(fmaf(s4.x, bf2f(uv.x), t4.x), 0.f);
    acc.y += fmaxf(fmaf(s4.y, bf2f(uv.y), t4.y), 0.f);
    acc.z += fmaxf(fmaf(s4.z, bf2f(uv.z), t4.z), 0.f);
    acc.w += fmaxf(fmaf(s4.w, bf2f(uv.w), t4.w), 0.f);
  }
  float inv = 1.0f / fmaxf((float)(hi - lo), 1.0f);
  acc.x *= inv; acc.y *= inv; acc.z *= inv; acc.w *= inv;
  *(f4*)(pooled + (size_t)g*HD + c) = acc;
}

// ---------------- head ----------------
__global__ __launch_bounds__(128) void k_head(const float* __restrict__ pooled,
    const float* __restrict__ W1, const float* __restrict__ b1,
    const float* __restrict__ W2, const float* __restrict__ b2, float* __restrict__ out)
{
  __shared__ float p[HD];
  __shared__ float red[2];
  int g = blockIdx.x, t = threadIdx.x;
  if(t < 64) *(f4*)&p[t*4] = *(const f4*)(pooled + (size_t)g*HD + t*4);
  __syncthreads();
  float s = b1[t];
  for(int k=0;k<HD;k++) s = fmaf(p[k], W1[k*128 + t], s);
  float o = fmaxf(s, 0.f) * W2[t];
  #pragma unroll
  for(int d=1; d<64; d<<=1) o += __shfl_xor(o, d, 64);
  if((t & 63) == 0) red[t>>6] = o;
  __syncthreads();
  if(t == 0) out[g] = red[0] + red[1] + b2[0];
}

// ---------------- launch ----------------
extern "C" void kernel_launch(void* const* d_in, const int* in_sizes, int n_in,
                              void* d_out, int out_size, void* d_ws, size_t ws_size,
                              hipStream_t stream) {
  const float* x    = (const float*)d_in[0];
  const int*   ei   = (const int*)  d_in[1];
  const int*   bat  = (const int*)  d_in[2];
  const float* inW  = (const float*)d_in[3];
  const float* inb  = (const float*)d_in[4];
  const float* W1   = (const float*)d_in[5];
  const float* b1   = (const float*)d_in[6];
  const float* g1   = (const float*)d_in[7];
  const float* be1  = (const float*)d_in[8];
  const float* W2   = (const float*)d_in[9];
  const float* b2   = (const float*)d_in[10];
  const float* g2   = (const float*)d_in[11];
  const float* be2  = (const float*)d_in[12];
  const float* eps  = (const float*)d_in[13];
  const float* hW1  = (const float*)d_in[14];
  const float* hb1  = (const float*)d_in[15];
  const float* hW2  = (const float*)d_in[16];
  const float* hb2  = (const float*)d_in[17];
  float* out = (float*)d_out;

  char* p = (char*)d_ws;
  auto alloc = [&](size_t bytes)->char*{
    char* r = p; p += (bytes + 255) & ~(size_t)255; return r;
  };
  unsigned short* B0 = (unsigned short*)alloc((size_t)MPAD*HD*2);
  unsigned short* B1 = (unsigned short*)alloc((size_t)MPAD*HD*2);
  unsigned short* Wtin = (unsigned short*)alloc((size_t)FINDIM*HD*2);
  unsigned short* Wt1  = (unsigned short*)alloc((size_t)NLAYER*HD*HD*2);
  unsigned short* Wt2  = (unsigned short*)alloc((size_t)NLAYER*HD*HD*2);
  int* counts  = (int*)alloc((size_t)NN*4);
  int* offsets = (int*)alloc((size_t)(NN+1)*4);
  int* cursor  = (int*)alloc((size_t)NN*4);
  int* eidx    = (int*)alloc((size_t)NE*4);
  int* partials= (int*)alloc(128*4);
  float* cs    = (float*)alloc(4*HD*4);     // cs1 = cs, cs2 = cs + 2*HD
  float* pooled= (float*)alloc((size_t)NG*HD*4);

  float* cs1 = cs;
  float* cs2 = cs + 2*HD;

  // CSR build
  k_zero<<<(NN+255)/256, 256, 0, stream>>>(counts, NN);
  k_count<<<(NE+255)/256, 256, 0, stream>>>(ei, counts);
  int nb = (NN + 1023)/1024;
  k_scan_partial<<<nb, 256, 0, stream>>>(counts, partials);
  k_scan_tot<<<1, 128, 0, stream>>>(partials, offsets, nb);
  k_scan_final<<<nb, 256, 0, stream>>>(counts, partials, offsets, cursor);
  k_fill<<<(NE+255)/256, 256, 0, stream>>>(ei, cursor, eidx);

  // weights -> bf16 [n][k]
  k_wt<<<dim3((FINDIM*HD+255)/256, 1), 256, 0, stream>>>(inW, Wtin, FINDIM, HD);
  k_wt<<<dim3((HD*HD+255)/256, NLAYER), 256, 0, stream>>>(W1, Wt1, HD, HD);
  k_wt<<<dim3((HD*HD+255)/256, NLAYER), 256, 0, stream>>>(W2, Wt2, HD, HD);

  k_gemmb_in<<<2*MG, 256, 0, stream>>>(x, Wtin, inb, B0);

  unsigned short* hbuf = B0;
  unsigned short* tbuf = B1;
  for(int l=0; l<NLAYER; l++){
    // k_agg: applies BN2(l-1)+ReLU to src (ident for l==0); zeroes cs1
    const float* pb  = (l > 0) ? (b2  + (l-1)*HD) : b2;
    const float* pg  = (l > 0) ? (g2  + (l-1)*HD) : g2;
    const float* pbe = (l > 0) ? (be2 + (l-1)*HD) : be2;
    k_agg<<<(NN+3)/4, 256, 0, stream>>>(hbuf, tbuf, offsets, eidx, eps, l,
                                        cs2, pb, pg, pbe, cs1, l==0 ? 1 : 0);
    // gemm1: raw linear1 + stats -> cs1; zeroes cs2
    k_gemmb<0, false, true><<<2*MG, 256, 0, stream>>>(tbuf, Wt1 + (size_t)l*HD*HD, b1 + l*HD,
                                                      nullptr, nullptr, nullptr, nullptr,
                                                      hbuf, cs1, cs2);
    // gemm2: TRANS = inline BN1(l)+ReLU on A; stats -> cs2
    k_gemmb<1, false, true><<<2*MG, 256, 0, stream>>>(hbuf, Wt2 + (size_t)l*HD*HD, b2 + l*HD,
                                                      cs1, b1 + l*HD, g1 + l*HD, be1 + l*HD,
                                                      tbuf, cs2, nullptr);
    unsigned short* tmp = hbuf; hbuf = tbuf; tbuf = tmp;
  }

  // pool: applies BN2(last)+ReLU inline from cs2
  k_pool<<<(NG+3)/4, 256, 0, stream>>>(hbuf, bat, cs2, b2 + (NLAYER-1)*HD,
                                       g2 + (NLAYER-1)*HD, be2 + (NLAYER-1)*HD, pooled);
  k_head<<<NG, 128, 0, stream>>>(pooled, hW1, hb1, hW2, hb2, out);
}

// Round 8
// 789.857 us; speedup vs baseline: 1.3376x; 1.0366x over previous
//
#include <hip/hip_runtime.h>
#include <hip/hip_bf16.h>
#include <stdint.h>
#include <stddef.h>

#define NN 100000
#define NE 300000
#define FINDIM 128
#define HD 256
#define NG 4000
#define NLAYER 5
#define MPAD 100096   // multiple of 32; NN%32==0 so tiles are fully real or fully pad
#define NT (MPAD/32)  // 3128 m-tiles of 32 rows
#define MG 384        // m-groups; grid = 2*MG

typedef __attribute__((ext_vector_type(8))) short bf8;
typedef __attribute__((ext_vector_type(4))) float f4;

#define FENCE() __asm__ volatile("" ::: "memory")
#define WAITVM2() __asm__ volatile("s_waitcnt vmcnt(2)" ::: "memory")
#define WAITVM4() __asm__ volatile("s_waitcnt vmcnt(4)" ::: "memory")
#define WAITVM6() __asm__ volatile("s_waitcnt vmcnt(6)" ::: "memory")
#define WAITLGKM() __asm__ volatile("s_waitcnt lgkmcnt(0)" ::: "memory")
#define BARRIER() do { FENCE(); __builtin_amdgcn_s_barrier(); FENCE(); } while(0)

__device__ __forceinline__ unsigned short f2bf(float f){
  union { float f; unsigned u; } uf; uf.f = f;
  unsigned r = uf.u + 0x7fffu + ((uf.u >> 16) & 1u);
  return (unsigned short)(r >> 16);
}
__device__ __forceinline__ float bf2f(unsigned short h){
  union { unsigned u; float f; } uf; uf.u = ((unsigned)h) << 16; return uf.f;
}

__device__ __forceinline__ void gload16(const void* g, void* l){
  __builtin_amdgcn_global_load_lds((const __attribute__((address_space(1))) void*)g,
                                   (__attribute__((address_space(3))) void*)l, 16, 0, 0);
}

// inline BN finalize: raw bias-free sums -> scale/shift for one channel
__device__ __forceinline__ void bncoef(const float* __restrict__ st,
                                       const float* __restrict__ bb,
                                       const float* __restrict__ gg,
                                       const float* __restrict__ be,
                                       int ch, float& s, float& sh){
  float m0 = st[ch] * (1.0f/NN);
  float mean = m0 + bb[ch];
  float var  = st[HD + ch] * (1.0f/NN) - m0*m0;
  s  = gg[ch] * rsqrtf(var + 1e-5f);
  sh = be[ch] - mean*s;
}

// ---------------- zero fill ----------------
__global__ void k_zero(int* __restrict__ p, int n){
  int i = blockIdx.x*256 + threadIdx.x;
  if(i < n) p[i] = 0;
}

// ---------------- CSR build ----------------
__global__ void k_count(const int* __restrict__ ei, int* __restrict__ counts){
  int e = blockIdx.x*256 + threadIdx.x;
  if(e < NE) atomicAdd(&counts[ei[NE + e]], 1);
}

__global__ void k_scan_partial(const int* __restrict__ counts, int* __restrict__ partials){
  __shared__ int sw[4];
  int b = blockIdx.x, t = threadIdx.x;
  int base = b*1024 + t*4;
  int s = 0;
  #pragma unroll
  for(int j=0;j<4;j++){ int i = base+j; if(i < NN) s += counts[i]; }
  #pragma unroll
  for(int d=1; d<64; d<<=1) s += __shfl_xor(s, d, 64);
  if((t & 63) == 0) sw[t>>6] = s;
  __syncthreads();
  if(t == 0) partials[b] = sw[0]+sw[1]+sw[2]+sw[3];
}

__global__ void k_scan_tot(int* __restrict__ partials, int* __restrict__ offsets, int nb){
  __shared__ int sm[128];
  int t = threadIdx.x;
  int v = (t < nb) ? partials[t] : 0;
  sm[t] = v; __syncthreads();
  for(int d=1; d<128; d<<=1){
    int x = 0;
    if(t >= d) x = sm[t-d];
    __syncthreads();
    sm[t] += x;
    __syncthreads();
  }
  if(t < nb) partials[t] = sm[t] - v;   // exclusive
  if(t == 127) offsets[NN] = sm[127];   // total == NE
}

__global__ void k_scan_final(const int* __restrict__ counts, const int* __restrict__ partials,
                             int* __restrict__ offsets, int* __restrict__ cursor){
  __shared__ int wsum[4];
  int b = blockIdx.x, t = threadIdx.x;
  int base = b*1024 + t*4;
  int c[4]; int ts = 0;
  #pragma unroll
  for(int j=0;j<4;j++){ int i = base+j; c[j] = (i < NN) ? counts[i] : 0; ts += c[j]; }
  int lane = t & 63;
  int inc = ts;
  #pragma unroll
  for(int d=1; d<64; d<<=1){ int x = __shfl_up(inc, d, 64); if(lane >= d) inc += x; }
  if(lane == 63) wsum[t>>6] = inc;
  __syncthreads();
  int woff = 0;
  for(int w2=0; w2<(t>>6); w2++) woff += wsum[w2];
  int excl = partials[b] + woff + inc - ts;
  #pragma unroll
  for(int j=0;j<4;j++){
    int i = base+j;
    if(i < NN){ offsets[i] = excl; cursor[i] = excl; excl += c[j]; }
  }
}

__global__ void k_fill(const int* __restrict__ ei, int* __restrict__ cursor, int* __restrict__ eidx){
  int e = blockIdx.x*256 + threadIdx.x;
  if(e < NE){
    int d = ei[NE + e];
    int pos = atomicAdd(&cursor[d], 1);
    eidx[pos] = ei[e];
  }
}

// ---------------- weight transpose/convert ----------------
__global__ void k_wt(const float* __restrict__ src, unsigned short* __restrict__ dst, int K, int Ncols){
  int l = blockIdx.y;
  size_t base = (size_t)l * K * Ncols;
  int i = blockIdx.x*256 + threadIdx.x;
  if(i < K*Ncols){
    int k = i / Ncols, n = i % Ncols;
    dst[base + (size_t)n*K + k] = f2bf(src[base + i]);
  }
}

// ---------------- GEMM, B-in-regs, triple-buffered A, ONE barrier per tile ----------------
// R2-verified schedule (43.3us): 3 rotating 16KB A-buffers, counted vmcnt
// (steady 6 / first 4 / last 2), single top barrier per tile, DMA(k+2) into
// buf[(k-1)%3] after the body. launch_bounds(256,3): VGPR ~84, no spill
// (R6 lesson: (256,4) made the compiler pick 64 VGPR and spill bb[]).
// TRANS: BN coef inline from raw stats (amortized over 8-tile body).
// zstats: block 0 zeroes the NEXT stats buffer (k_zero launches deleted).
template<int TRANS, bool RELUOUT, bool STATS>
__global__ __launch_bounds__(256, 3) void k_gemmb(
    const unsigned short* __restrict__ A, const unsigned short* __restrict__ Bt,
    const float* __restrict__ bias, const float* __restrict__ bstats,
    const float* __restrict__ bnb, const float* __restrict__ bng,
    const float* __restrict__ bnbe, unsigned short* __restrict__ C,
    float* __restrict__ stats, float* __restrict__ zstats)
{
  __shared__ __align__(16) unsigned short As[3][8192];   // 48 KB: 3 x (32r x 256k)
  __shared__ __align__(16) unsigned short Cs[4][576];    // 4.5 KB: per-wave 16 x 36
  const int t = threadIdx.x;
  const int lane = t & 63, w = t >> 6;
  const int q = lane >> 4, ln = lane & 15;
  const int nh = blockIdx.x & 1;
  const int mg = blockIdx.x >> 1;
  const int nbase = nh*128 + w*32;

  if(zstats && blockIdx.x == 0){ zstats[t] = 0.f; zstats[256 + t] = 0.f; }

  // B fragments resident in registers (L2-resident 128 KB weight)
  bf8 bb[2][8];
  #pragma unroll
  for(int nf=0; nf<2; nf++)
    #pragma unroll
    for(int s=0; s<8; s++)
      bb[nf][s] = *(const bf8*)(Bt + (size_t)(nbase + nf*16 + ln)*HD + s*32 + q*8);

  float bv[2];
  #pragma unroll
  for(int nf=0; nf<2; nf++) bv[nf] = bias[nbase + nf*16 + ln];

  // TRANS scale/shift computed inline from raw stats (16 VGPR resident)
  f4 sA = (f4){0.f,0.f,0.f,0.f}, sB = sA, tA = sA, tB = sA;
  if(TRANS){
    int cc = (t & 31) * 8;
    #pragma unroll
    for(int e=0; e<8; e++){
      float sv, sh;
      bncoef(bstats, bnb, bng, bnbe, cc + e, sv, sh);
      if(e < 4){ sA[e] = sv; tA[e] = sh; }
      else     { sB[e-4] = sv; tB[e-4] = sh; }
    }
  }

  auto issueA = [&](int mt, int b){
    const int m0 = mt*32;
    #pragma unroll
    for(int j=0; j<4; j++){
      int slot = j*256 + t;
      int row = slot >> 5, p = slot & 31;
      int c = p ^ (row & 7);
      gload16(A + (size_t)(m0 + row)*HD + c*8, &As[b][(j*256 + w*64)*8]);
    }
  };

  float sacc[2] = {0.f, 0.f}, ssacc[2] = {0.f, 0.f};

  issueA(mg, 0);
  issueA(mg + MG, 1);           // mg+MG < NT always (mg<384, NT=3128)

  int k = 0;
  for(int mt = mg; mt < NT; mt += MG, k++){
    const bool last = (mt + MG >= NT);
    // retire DMA(k); keep DMA(k+1) + prior stores in flight
    if(last)        WAITVM2();
    else if(k == 0) WAITVM4();
    else            WAITVM6();
    BARRIER();                          // tile k in LDS everywhere; tile k-1 fully read

    unsigned short* Ab = &As[k % 3][0];
    const int m0 = mt*32;
    const bool padt = (m0 >= NN);       // block-uniform; pad tiles are trailing

    if(padt){
      // keep output pad rows zero; skip compute/stats
      uint4 z = (uint4){0u,0u,0u,0u};
      int r2 = lane >> 2, sg = lane & 3;
      *(uint4*)&C[(size_t)(m0 + r2)*HD + nbase + sg*8]      = z;
      *(uint4*)&C[(size_t)(m0 + 16 + r2)*HD + nbase + sg*8] = z;
    } else {
      if(TRANS){
        // one-pass in-LDS BN+ReLU, scale/shift from regs, conflict-free sweep
        const int r0 = t >> 5;
        const int p  = (t & 31) ^ r0;
        #pragma unroll
        for(int i=0; i<4; i++){
          int row = r0 + 8*i;
          uint4 u = *(uint4*)&Ab[(row*32 + p)*8];
          unsigned short* us = (unsigned short*)&u;
          #pragma unroll
          for(int e=0; e<8; e++){
            float sc = (e<4) ? sA[e] : sB[e-4];
            float sh = (e<4) ? tA[e] : tB[e-4];
            float v = bf2f(us[e]);
            v = fmaxf(fmaf(sc, v, sh), 0.f);
            us[e] = f2bf(v);
          }
          *(uint4*)&Ab[(row*32 + p)*8] = u;
        }
        WAITLGKM();
        BARRIER();                      // transformed tile visible to all waves
      }

      f4 acc[2][2];
      #pragma unroll
      for(int i=0;i<2;i++)
        #pragma unroll
        for(int j=0;j<2;j++) acc[i][j] = (f4){0.f,0.f,0.f,0.f};

      __builtin_amdgcn_s_setprio(1);
      #pragma unroll
      for(int s=0; s<8; s++){
        bf8 af[2];
        #pragma unroll
        for(int mi=0; mi<2; mi++){
          int row = mi*16 + ln;
          int p = (s*4 + q) ^ (row & 7);
          af[mi] = *(const bf8*)&Ab[row*256 + p*8];
        }
        #pragma unroll
        for(int mi=0; mi<2; mi++)
          #pragma unroll
          for(int nf=0; nf<2; nf++)
            acc[mi][nf] = __builtin_amdgcn_mfma_f32_16x16x32_bf16(af[mi], bb[nf][s], acc[mi][nf], 0, 0, 0);
      }
      __builtin_amdgcn_s_setprio(0);

      if(STATS){
        #pragma unroll
        for(int nf=0; nf<2; nf++)
          #pragma unroll
          for(int mi=0; mi<2; mi++)
            #pragma unroll
            for(int r=0; r<4; r++){
              float v = acc[mi][nf][r];
              sacc[nf] += v; ssacc[nf] = fmaf(v, v, ssacc[nf]);
            }
      }

      // epilogue: two 16-row half-passes through a 4.5KB per-wave Cs slice
      unsigned short* wsc = &Cs[w][0];
      #pragma unroll
      for(int mi=0; mi<2; mi++){
        #pragma unroll
        for(int nf=0; nf<2; nf++)
          #pragma unroll
          for(int r=0; r<4; r++){
            float v = acc[mi][nf][r] + bv[nf];
            if(RELUOUT) v = fmaxf(v, 0.f);
            wsc[(q*4 + r)*36 + nf*16 + ln] = f2bf(v);
          }
        int r2 = lane >> 2, sg = lane & 3;
        uint4 u = *(const uint4*)&wsc[r2*36 + sg*8];
        *(uint4*)&C[(size_t)(m0 + mi*16 + r2)*HD + nbase + sg*8] = u;
      }
    }

    // DMA(k+2) into buf[(k+2)%3] == buf[(k-1)%3]: safe, all waves passed the
    // top barrier of k, so tile k-1 is fully consumed. No second barrier.
    FENCE();
    if(mt + 2*MG < NT) issueA(mt + 2*MG, (k+2) % 3);
  }

  if(STATS){
    #pragma unroll
    for(int nf=0; nf<2; nf++){
      float s = sacc[nf], ss = ssacc[nf];
      s  += __shfl_xor(s, 16, 64);  s  += __shfl_xor(s, 32, 64);
      ss += __shfl_xor(ss, 16, 64); ss += __shfl_xor(ss, 32, 64);
      if(q == 0){
        int gn = nbase + nf*16 + ln;
        atomicAdd(&stats[gn], s);
        atomicAdd(&stats[HD + gn], ss);
      }
    }
  }
}

// ---------------- input projection (f32 A, K=128), B-in-registers ----------------
__global__ __launch_bounds__(256, 3) void k_gemmb_in(
    const float* __restrict__ A, const unsigned short* __restrict__ Bt,
    const float* __restrict__ bias, unsigned short* __restrict__ C)
{
  __shared__ __align__(16) unsigned short As[4096];      // 32 rows x 128 k = 8 KB
  __shared__ __align__(16) unsigned short Cs[4][1152];
  const int t = threadIdx.x;
  const int lane = t & 63, w = t >> 6;
  const int q = lane >> 4, ln = lane & 15;
  const int nh = blockIdx.x & 1;
  const int mg = blockIdx.x >> 1;
  const int nbase = nh*128 + w*32;

  bf8 bb[2][4];
  #pragma unroll
  for(int nf=0; nf<2; nf++)
    #pragma unroll
    for(int s=0; s<4; s++)
      bb[nf][s] = *(const bf8*)(Bt + (size_t)(nbase + nf*16 + ln)*FINDIM + s*32 + q*8);

  float bv[2];
  #pragma unroll
  for(int nf=0; nf<2; nf++) bv[nf] = bias[nbase + nf*16 + ln];

  for(int mt = mg; mt < NT; mt += MG){
    const int m0 = mt*32;
    const bool padt = (m0 >= NN);
    __syncthreads();
    #pragma unroll
    for(int j=0; j<2; j++){
      int slot = j*256 + t;
      int row = slot >> 4, p = slot & 15;
      int c = p ^ (row & 7);
      int gm = m0 + row;
      f4 v0 = (f4){0.f,0.f,0.f,0.f}, v1 = (f4){0.f,0.f,0.f,0.f};
      if(gm < NN){
        v0 = *(const f4*)&A[(size_t)gm*FINDIM + c*8];
        v1 = *(const f4*)&A[(size_t)gm*FINDIM + c*8 + 4];
      }
      ushort4 a0, a1;
      a0.x = f2bf(v0.x); a0.y = f2bf(v0.y); a0.z = f2bf(v0.z); a0.w = f2bf(v0.w);
      a1.x = f2bf(v1.x); a1.y = f2bf(v1.y); a1.z = f2bf(v1.z); a1.w = f2bf(v1.w);
      *(ushort4*)&As[row*128 + p*8]     = a0;
      *(ushort4*)&As[row*128 + p*8 + 4] = a1;
    }
    __syncthreads();

    f4 acc[2][2];
    #pragma unroll
    for(int i=0;i<2;i++)
      #pragma unroll
      for(int j=0;j<2;j++) acc[i][j] = (f4){0.f,0.f,0.f,0.f};

    #pragma unroll
    for(int s=0; s<4; s++){
      bf8 af[2];
      #pragma unroll
      for(int mi=0; mi<2; mi++){
        int row = mi*16 + ln;
        int p = (s*4 + q) ^ (row & 7);
        af[mi] = *(const bf8*)&As[row*128 + p*8];
      }
      #pragma unroll
      for(int mi=0; mi<2; mi++)
        #pragma unroll
        for(int nf=0; nf<2; nf++)
          acc[mi][nf] = __builtin_amdgcn_mfma_f32_16x16x32_bf16(af[mi], bb[nf][s], acc[mi][nf], 0, 0, 0);
    }

    unsigned short* wsc = &Cs[w][0];
    #pragma unroll
    for(int mi=0; mi<2; mi++)
      #pragma unroll
      for(int nf=0; nf<2; nf++)
        #pragma unroll
        for(int r=0; r<4; r++){
          float v = fmaxf(acc[mi][nf][r] + bv[nf], 0.f);
          if(padt) v = 0.f;
          wsc[(mi*16 + q*4 + r)*36 + nf*16 + ln] = f2bf(v);
        }
    int r2 = lane >> 1, ch = lane & 1;
    size_t cb = (size_t)(m0 + r2)*HD + nh*128 + w*32;
    uint4 u0 = *(const uint4*)&wsc[r2*36 + ch*8];
    uint4 u1 = *(const uint4*)&wsc[r2*36 + (ch+2)*8];
    *(uint4*)&C[cb + ch*8]     = u0;
    *(uint4*)&C[cb + (ch+2)*8] = u1;
  }
}

// ---------------- aggregation: half-wave split, 16B lanes; BN coef via LDS ----------------
// R7 lesson: per-thread 8x bncoef prologue (8 rsqrt + ~40 loads/thread)
// nearly doubled the VALU work of this kernel (43->60us, VALUBusy 63->76%).
// Fix: 256 threads each compute ONE channel's coef into a 2KB LDS table
// (1 rsqrt + 5 loads/thread), one barrier, then 4x f4 LDS reads per lane.
__device__ __forceinline__ void acc8(f4& alo, f4& ahi, uint4 u, float wt,
                                     f4 s0, f4 s1, f4 t0, f4 t1, int ident){
  const unsigned short* us = (const unsigned short*)&u;
  float v[8];
  #pragma unroll
  for(int e=0;e<8;e++) v[e] = bf2f(us[e]);
  if(!ident){
    v[0] = fmaxf(fmaf(s0.x, v[0], t0.x), 0.f);
    v[1] = fmaxf(fmaf(s0.y, v[1], t0.y), 0.f);
    v[2] = fmaxf(fmaf(s0.z, v[2], t0.z), 0.f);
    v[3] = fmaxf(fmaf(s0.w, v[3], t0.w), 0.f);
    v[4] = fmaxf(fmaf(s1.x, v[4], t1.x), 0.f);
    v[5] = fmaxf(fmaf(s1.y, v[5], t1.y), 0.f);
    v[6] = fmaxf(fmaf(s1.z, v[6], t1.z), 0.f);
    v[7] = fmaxf(fmaf(s1.w, v[7], t1.w), 0.f);
  }
  alo.x = fmaf(wt, v[0], alo.x); alo.y = fmaf(wt, v[1], alo.y);
  alo.z = fmaf(wt, v[2], alo.z); alo.w = fmaf(wt, v[3], alo.w);
  ahi.x = fmaf(wt, v[4], ahi.x); ahi.y = fmaf(wt, v[5], ahi.y);
  ahi.z = fmaf(wt, v[6], ahi.z); ahi.w = fmaf(wt, v[7], ahi.w);
}

__global__ __launch_bounds__(256) void k_agg(const unsigned short* __restrict__ src,
    unsigned short* __restrict__ dst,
    const int* __restrict__ offs, const int* __restrict__ eidx,
    const float* __restrict__ eps, int l,
    const float* __restrict__ bstats, const float* __restrict__ bnb,
    const float* __restrict__ bng, const float* __restrict__ bnbe,
    float* __restrict__ zstats, int ident)
{
  __shared__ float scsh[512];           // 256 scale + 256 shift

  if(blockIdx.x == 0){ zstats[threadIdx.x] = 0.f; zstats[256 + threadIdx.x] = 0.f; }

  if(!ident){
    float sv, sh;
    bncoef(bstats, bnb, bng, bnbe, threadIdx.x, sv, sh);
    scsh[threadIdx.x] = sv; scsh[256 + threadIdx.x] = sh;
    __syncthreads();
  }

  int wv = threadIdx.x >> 6;
  int n = blockIdx.x*4 + wv;
  if(n >= NN) return;
  int lane = threadIdx.x & 63;
  int h = lane >> 5, l5 = lane & 31;
  int c = l5 * 8;

  f4 s0=(f4){0.f,0.f,0.f,0.f}, s1=s0, t0=s0, t1=s0;
  if(!ident){
    s0 = *(const f4*)&scsh[c];       s1 = *(const f4*)&scsh[c + 4];
    t0 = *(const f4*)&scsh[256 + c]; t1 = *(const f4*)&scsh[256 + c + 4];
  }
  float ep = 1.f + eps[l];

  f4 alo = (f4){0.f,0.f,0.f,0.f}, ahi = alo;
  int lo = offs[n], hi = offs[n+1];

  bool first = true;
  for(int base = lo; first || base < hi; base += 64){
    int cnt = hi - base; if(cnt > 64) cnt = 64; if(cnt < 0) cnt = 0;
    int R = cnt + (first ? 1 : 0);          // virtual rows (self included once)
    int idx = (base + lane < hi) ? eidx[base + lane] : 0;
    for(int r0 = 0; r0 < R; r0 += 4){
      int my0 = r0 + h, my1 = r0 + 2 + h;
      bool v0 = my0 < R, v1 = my1 < R;
      bool self0 = first && (my0 == 0);
      int j0 = (first ? my0 - 1 : my0) & 63;
      int j1 = (first ? my1 - 1 : my1) & 63;
      int sr0 = __shfl(idx, j0, 64);
      int sr1 = __shfl(idx, j1, 64);
      int row0 = self0 ? n : sr0;
      float w0 = self0 ? ep : 1.f;
      uint4 u0, u1;
      if(v0) u0 = *(const uint4*)(src + (size_t)row0*HD + c);
      if(v1) u1 = *(const uint4*)(src + (size_t)sr1*HD + c);
      if(v0) acc8(alo, ahi, u0, w0, s0, s1, t0, t1, ident);
      if(v1) acc8(alo, ahi, u1, 1.f, s0, s1, t0, t1, ident);
    }
    first = false;
  }

  // merge the two halves (lane l and l^32 hold the same channel set)
  #pragma unroll
  for(int e=0;e<4;e++){
    alo[e] += __shfl_xor(alo[e], 32, 64);
    ahi[e] += __shfl_xor(ahi[e], 32, 64);
  }
  if(h == 0){
    unsigned short o[8];
    o[0]=f2bf(alo.x); o[1]=f2bf(alo.y); o[2]=f2bf(alo.z); o[3]=f2bf(alo.w);
    o[4]=f2bf(ahi.x); o[5]=f2bf(ahi.y); o[6]=f2bf(ahi.z); o[7]=f2bf(ahi.w);
    *(uint4*)(dst + (size_t)n*HD + c) = *(const uint4*)o;
  }
}

// ---------------- pooling (inline BN coef; 4/thread, tiny kernel) ----------------
__device__ __forceinline__ int lowb(const int* __restrict__ arr, int n, int key){
  int lo = 0, hi = n;
  while(lo < hi){ int mid = (lo + hi) >> 1; if(arr[mid] < key) lo = mid + 1; else hi = mid; }
  return lo;
}

__global__ __launch_bounds__(256) void k_pool(const unsigned short* __restrict__ src,
    const int* __restrict__ batch,
    const float* __restrict__ bstats, const float* __restrict__ bnb,
    const float* __restrict__ bng, const float* __restrict__ bnbe,
    float* __restrict__ pooled)
{
  int wv = threadIdx.x >> 6;
  int g = blockIdx.x*4 + wv;
  if(g >= NG) return;
  int lane = threadIdx.x & 63;
  int c = lane << 2;
  int lo = lowb(batch, NN, g);
  int hi = lowb(batch, NN, g+1);
  f4 s4, t4;
  #pragma unroll
  for(int e=0; e<4; e++){
    float sv, sh;
    bncoef(bstats, bnb, bng, bnbe, c + e, sv, sh);
    s4[e] = sv; t4[e] = sh;
  }
  f4 acc = (f4){0.f,0.f,0.f,0.f};
  for(int n=lo; n<hi; n++){
    ushort4 uv = *(const ushort4*)(src + (size_t)n*HD + c);
    acc.x += fmaxf(fmaf(s4.x, bf2f(uv.x), t4.x), 0.f);
    acc.y += fmaxf(fmaf(s4.y, bf2f(uv.y), t4.y), 0.f);
    acc.z += fmaxf(fmaf(s4.z, bf2f(uv.z), t4.z), 0.f);
    acc.w += fmaxf(fmaf(s4.w, bf2f(uv.w), t4.w), 0.f);
  }
  float inv = 1.0f / fmaxf((float)(hi - lo), 1.0f);
  acc.x *= inv; acc.y *= inv; acc.z *= inv; acc.w *= inv;
  *(f4*)(pooled + (size_t)g*HD + c) = acc;
}

// ---------------- head ----------------
__global__ __launch_bounds__(128) void k_head(const float* __restrict__ pooled,
    const float* __restrict__ W1, const float* __restrict__ b1,
    const float* __restrict__ W2, const float* __restrict__ b2, float* __restrict__ out)
{
  __shared__ float p[HD];
  __shared__ float red[2];
  int g = blockIdx.x, t = threadIdx.x;
  if(t < 64) *(f4*)&p[t*4] = *(const f4*)(pooled + (size_t)g*HD + t*4);
  __syncthreads();
  float s = b1[t];
  for(int k=0;k<HD;k++) s = fmaf(p[k], W1[k*128 + t], s);
  float o = fmaxf(s, 0.f) * W2[t];
  #pragma unroll
  for(int d=1; d<64; d<<=1) o += __shfl_xor(o, d, 64);
  if((t & 63) == 0) red[t>>6] = o;
  __syncthreads();
  if(t == 0) out[g] = red[0] + red[1] + b2[0];
}

// ---------------- launch ----------------
extern "C" void kernel_launch(void* const* d_in, const int* in_sizes, int n_in,
                              void* d_out, int out_size, void* d_ws, size_t ws_size,
                              hipStream_t stream) {
  const float* x    = (const float*)d_in[0];
  const int*   ei   = (const int*)  d_in[1];
  const int*   bat  = (const int*)  d_in[2];
  const float* inW  = (const float*)d_in[3];
  const float* inb  = (const float*)d_in[4];
  const float* W1   = (const float*)d_in[5];
  const float* b1   = (const float*)d_in[6];
  const float* g1   = (const float*)d_in[7];
  const float* be1  = (const float*)d_in[8];
  const float* W2   = (const float*)d_in[9];
  const float* b2   = (const float*)d_in[10];
  const float* g2   = (const float*)d_in[11];
  const float* be2  = (const float*)d_in[12];
  const float* eps  = (const float*)d_in[13];
  const float* hW1  = (const float*)d_in[14];
  const float* hb1  = (const float*)d_in[15];
  const float* hW2  = (const float*)d_in[16];
  const float* hb2  = (const float*)d_in[17];
  float* out = (float*)d_out;

  char* p = (char*)d_ws;
  auto alloc = [&](size_t bytes)->char*{
    char* r = p; p += (bytes + 255) & ~(size_t)255; return r;
  };
  unsigned short* B0 = (unsigned short*)alloc((size_t)MPAD*HD*2);
  unsigned short* B1 = (unsigned short*)alloc((size_t)MPAD*HD*2);
  unsigned short* Wtin = (unsigned short*)alloc((size_t)FINDIM*HD*2);
  unsigned short* Wt1  = (unsigned short*)alloc((size_t)NLAYER*HD*HD*2);
  unsigned short* Wt2  = (unsigned short*)alloc((size_t)NLAYER*HD*HD*2);
  int* counts  = (int*)alloc((size_t)NN*4);
  int* offsets = (int*)alloc((size_t)(NN+1)*4);
  int* cursor  = (int*)alloc((size_t)NN*4);
  int* eidx    = (int*)alloc((size_t)NE*4);
  int* partials= (int*)alloc(128*4);
  float* cs    = (float*)alloc(4*HD*4);     // cs1 = cs, cs2 = cs + 2*HD
  float* pooled= (float*)alloc((size_t)NG*HD*4);

  float* cs1 = cs;
  float* cs2 = cs + 2*HD;

  // CSR build
  k_zero<<<(NN+255)/256, 256, 0, stream>>>(counts, NN);
  k_count<<<(NE+255)/256, 256, 0, stream>>>(ei, counts);
  int nb = (NN + 1023)/1024;
  k_scan_partial<<<nb, 256, 0, stream>>>(counts, partials);
  k_scan_tot<<<1, 128, 0, stream>>>(partials, offsets, nb);
  k_scan_final<<<nb, 256, 0, stream>>>(counts, partials, offsets, cursor);
  k_fill<<<(NE+255)/256, 256, 0, stream>>>(ei, cursor, eidx);

  // weights -> bf16 [n][k]
  k_wt<<<dim3((FINDIM*HD+255)/256, 1), 256, 0, stream>>>(inW, Wtin, FINDIM, HD);
  k_wt<<<dim3((HD*HD+255)/256, NLAYER), 256, 0, stream>>>(W1, Wt1, HD, HD);
  k_wt<<<dim3((HD*HD+255)/256, NLAYER), 256, 0, stream>>>(W2, Wt2, HD, HD);

  k_gemmb_in<<<2*MG, 256, 0, stream>>>(x, Wtin, inb, B0);

  unsigned short* hbuf = B0;
  unsigned short* tbuf = B1;
  for(int l=0; l<NLAYER; l++){
    // k_agg: applies BN2(l-1)+ReLU to src (ident for l==0); zeroes cs1
    const float* pb  = (l > 0) ? (b2  + (l-1)*HD) : b2;
    const float* pg  = (l > 0) ? (g2  + (l-1)*HD) : g2;
    const float* pbe = (l > 0) ? (be2 + (l-1)*HD) : be2;
    k_agg<<<(NN+3)/4, 256, 0, stream>>>(hbuf, tbuf, offsets, eidx, eps, l,
                                        cs2, pb, pg, pbe, cs1, l==0 ? 1 : 0);
    // gemm1: raw linear1 + stats -> cs1; zeroes cs2
    k_gemmb<0, false, true><<<2*MG, 256, 0, stream>>>(tbuf, Wt1 + (size_t)l*HD*HD, b1 + l*HD,
                                                      nullptr, nullptr, nullptr, nullptr,
                                                      hbuf, cs1, cs2);
    // gemm2: TRANS = inline BN1(l)+ReLU on A; stats -> cs2
    k_gemmb<1, false, true><<<2*MG, 256, 0, stream>>>(hbuf, Wt2 + (size_t)l*HD*HD, b2 + l*HD,
                                                      cs1, b1 + l*HD, g1 + l*HD, be1 + l*HD,
                                                      tbuf, cs2, nullptr);
    unsigned short* tmp = hbuf; hbuf = tbuf; tbuf = tmp;
  }

  // pool: applies BN2(last)+ReLU inline from cs2
  k_pool<<<(NG+3)/4, 256, 0, stream>>>(hbuf, bat, cs2, b2 + (NLAYER-1)*HD,
                                       g2 + (NLAYER-1)*HD, be2 + (NLAYER-1)*HD, pooled);
  k_head<<<NG, 128, 0, stream>>>(pooled, hW1, hb1, hW2, hb2, out);
}